// Round 3
// baseline (1874.485 us; speedup 1.0000x reference)
//
#include <hip/hip_runtime.h>

// EncoderTreeRNN fp32 baseline (resubmit r2 — infra failure, no bench data yet)

#define Hd 128            // hidden = embed = 128
#define NTOK 262144       // B*S = 4096*64
#define NB 4096           // batch

__device__ __forceinline__ float sigm(float x){
  return 1.0f / (1.0f + __expf(-x));
}
__device__ __forceinline__ float tanh_(float x){
  float xc = fminf(fmaxf(x, -15.0f), 15.0f);
  float e = __expf(2.0f * xc);
  return (e - 1.0f) / (e + 1.0f);
}

// Combined biases: bc[0:128)=bWz+bUzl+bUzr, bc[128:256)=bWr+bUrl+bUrr, bc[256:384)=bWh+bUhl+bUhr
__global__ void bias_combine_k(const float* bWz, const float* bUzl, const float* bUzr,
                               const float* bWr, const float* bUrl, const float* bUrr,
                               const float* bWh, const float* bUhl, const float* bUhr,
                               float* bc){
  int j = threadIdx.x;
  if (j < Hd){
    bc[j]          = bWz[j] + bUzl[j] + bUzr[j];
    bc[Hd + j]     = bWr[j] + bUrl[j] + bUrr[j];
    bc[2*Hd + j]   = bWh[j] + bUhl[j] + bUhr[j];
  }
}

// Level 0: hl=hr=0 -> z=sigm(x@Wz + bz), h~=tanh(x@Wh + bh)  (r is dead), out=(1-z)*h~
// Block: 256 thr, tile = 16 rows x 128 cols. Thread: 4 rows x 2 cols.
__global__ __launch_bounds__(256) void level0_k(
    const int* __restrict__ tokens, const float* __restrict__ emb,
    const float* __restrict__ Wz, const float* __restrict__ Wh,
    const float* __restrict__ bc, float* __restrict__ out)
{
  __shared__ __align__(16) float xs[16][Hd];
  const int tid = threadIdx.x;
  const int m0  = blockIdx.x * 16;
  for (int idx = tid; idx < 16*32; idx += 256){
    int r = idx >> 5, c = idx & 31;
    int tok = tokens[m0 + r];
    ((float4*)xs[r])[c] = ((const float4*)(emb + (size_t)tok * Hd))[c];
  }
  __syncthreads();
  const int c2 = tid & 63;   // column group -> cols j, j+1
  const int rg = tid >> 6;   // row group -> rows rg*4 .. rg*4+3
  const int j  = c2 * 2;
  const int r0 = rg * 4;

  float az[4][2] = {}; float ah[4][2] = {};
  for (int k = 0; k < Hd; k += 4){
    float a[4][4];
    *(float4*)a[0] = *(const float4*)(xs[r0+0] + k);
    *(float4*)a[1] = *(const float4*)(xs[r0+1] + k);
    *(float4*)a[2] = *(const float4*)(xs[r0+2] + k);
    *(float4*)a[3] = *(const float4*)(xs[r0+3] + k);
    #pragma unroll
    for (int kk = 0; kk < 4; kk++){
      float2 wz = *(const float2*)(Wz + (size_t)(k+kk)*Hd + j);
      float2 wh = *(const float2*)(Wh + (size_t)(k+kk)*Hd + j);
      #pragma unroll
      for (int r = 0; r < 4; r++){
        az[r][0] += a[r][kk] * wz.x;  az[r][1] += a[r][kk] * wz.y;
        ah[r][0] += a[r][kk] * wh.x;  ah[r][1] += a[r][kk] * wh.y;
      }
    }
  }
  const float bz0 = bc[j],        bz1 = bc[j+1];
  const float bh0 = bc[2*Hd + j], bh1 = bc[2*Hd + j + 1];
  #pragma unroll
  for (int r = 0; r < 4; r++){
    float z0 = sigm(az[r][0] + bz0), z1 = sigm(az[r][1] + bz1);
    float t0 = tanh_(ah[r][0] + bh0), t1 = tanh_(ah[r][1] + bh1);
    float2 v; v.x = (1.0f - z0) * t0; v.y = (1.0f - z1) * t1;
    *(float2*)(out + (size_t)(m0 + r0 + r) * Hd + j) = v;
  }
}

// Tree level: word=0.
// z = sigm(hl@Uzl + hr@Uzr + bz), r = sigm(hl@Url + hr@Urr + br)
// h~ = tanh((r*hl)@Uhl + (r*hr)@Uhr + bh), out = z*(hl+hr) + (1-z)*h~
// Block: 256 thr, tile = 16 out-rows (= 16 adjacent input-row pairs).
__global__ __launch_bounds__(256) void tree_k(
    const float* __restrict__ hin, float* __restrict__ hout,
    int lg_nout,
    const float* __restrict__ Uzl, const float* __restrict__ Uzr,
    const float* __restrict__ Url, const float* __restrict__ Urr,
    const float* __restrict__ Uhl, const float* __restrict__ Uhr,
    const float* __restrict__ bc)
{
  __shared__ __align__(16) float hl[16][Hd], hr[16][Hd], rl[16][Hd], rr[16][Hd];
  const int tid = threadIdx.x;
  const int m0  = blockIdx.x * 16;
  for (int idx = tid; idx < 16*32; idx += 256){
    int r = idx >> 5, c = idx & 31;
    int m = m0 + r;
    int b = m >> lg_nout;
    int i = m & ((1 << lg_nout) - 1);
    const float* base = hin + ((size_t)((b << (lg_nout + 1)) + 2*i)) * Hd;
    ((float4*)hl[r])[c] = ((const float4*)base)[c];
    ((float4*)hr[r])[c] = ((const float4*)(base + Hd))[c];
  }
  __syncthreads();
  const int c2 = tid & 63;
  const int rg = tid >> 6;
  const int j  = c2 * 2;
  const int r0 = rg * 4;

  float az[4][2] = {}, ar[4][2] = {};
  for (int k = 0; k < Hd; k += 4){
    float a[4][4], b_[4][4];
    *(float4*)a[0]  = *(const float4*)(hl[r0+0] + k);
    *(float4*)a[1]  = *(const float4*)(hl[r0+1] + k);
    *(float4*)a[2]  = *(const float4*)(hl[r0+2] + k);
    *(float4*)a[3]  = *(const float4*)(hl[r0+3] + k);
    *(float4*)b_[0] = *(const float4*)(hr[r0+0] + k);
    *(float4*)b_[1] = *(const float4*)(hr[r0+1] + k);
    *(float4*)b_[2] = *(const float4*)(hr[r0+2] + k);
    *(float4*)b_[3] = *(const float4*)(hr[r0+3] + k);
    #pragma unroll
    for (int kk = 0; kk < 4; kk++){
      float2 uzl = *(const float2*)(Uzl + (size_t)(k+kk)*Hd + j);
      float2 uzr = *(const float2*)(Uzr + (size_t)(k+kk)*Hd + j);
      float2 url = *(const float2*)(Url + (size_t)(k+kk)*Hd + j);
      float2 urr = *(const float2*)(Urr + (size_t)(k+kk)*Hd + j);
      #pragma unroll
      for (int r = 0; r < 4; r++){
        az[r][0] += a[r][kk]*uzl.x; az[r][0] += b_[r][kk]*uzr.x;
        az[r][1] += a[r][kk]*uzl.y; az[r][1] += b_[r][kk]*uzr.y;
        ar[r][0] += a[r][kk]*url.x; ar[r][0] += b_[r][kk]*urr.x;
        ar[r][1] += a[r][kk]*url.y; ar[r][1] += b_[r][kk]*urr.y;
      }
    }
  }
  float zv[4][2];
  #pragma unroll
  for (int r = 0; r < 4; r++){
    #pragma unroll
    for (int c = 0; c < 2; c++){
      float z  = sigm(az[r][c] + bc[j + c]);
      float rv = sigm(ar[r][c] + bc[Hd + j + c]);
      zv[r][c] = z;
      rl[r0+r][j+c] = rv * hl[r0+r][j+c];
      rr[r0+r][j+c] = rv * hr[r0+r][j+c];
    }
  }
  __syncthreads();
  float ahh[4][2] = {};
  for (int k = 0; k < Hd; k += 4){
    float a[4][4], b_[4][4];
    *(float4*)a[0]  = *(const float4*)(rl[r0+0] + k);
    *(float4*)a[1]  = *(const float4*)(rl[r0+1] + k);
    *(float4*)a[2]  = *(const float4*)(rl[r0+2] + k);
    *(float4*)a[3]  = *(const float4*)(rl[r0+3] + k);
    *(float4*)b_[0] = *(const float4*)(rr[r0+0] + k);
    *(float4*)b_[1] = *(const float4*)(rr[r0+1] + k);
    *(float4*)b_[2] = *(const float4*)(rr[r0+2] + k);
    *(float4*)b_[3] = *(const float4*)(rr[r0+3] + k);
    #pragma unroll
    for (int kk = 0; kk < 4; kk++){
      float2 uhl = *(const float2*)(Uhl + (size_t)(k+kk)*Hd + j);
      float2 uhr = *(const float2*)(Uhr + (size_t)(k+kk)*Hd + j);
      #pragma unroll
      for (int r = 0; r < 4; r++){
        ahh[r][0] += a[r][kk]*uhl.x; ahh[r][0] += b_[r][kk]*uhr.x;
        ahh[r][1] += a[r][kk]*uhl.y; ahh[r][1] += b_[r][kk]*uhr.y;
      }
    }
  }
  #pragma unroll
  for (int r = 0; r < 4; r++){
    float2 v;
    #pragma unroll
    for (int c = 0; c < 2; c++){
      float ht = tanh_(ahh[r][c] + bc[2*Hd + j + c]);
      float s  = hl[r0+r][j+c] + hr[r0+r][j+c];
      ((float*)&v)[c] = zv[r][c] * s + (1.0f - zv[r][c]) * ht;
    }
    *(float2*)(hout + (size_t)(m0 + r0 + r) * Hd + j) = v;
  }
}

extern "C" void kernel_launch(void* const* d_in, const int* in_sizes, int n_in,
                              void* d_out, int out_size, void* d_ws, size_t ws_size,
                              hipStream_t stream) {
  const int*   tokens = (const int*)  d_in[0];
  const float* emb    = (const float*)d_in[1];
  const float* Wz  = (const float*)d_in[2];  const float* bWz  = (const float*)d_in[3];
  const float* Uzl = (const float*)d_in[4];  const float* bUzl = (const float*)d_in[5];
  const float* Uzr = (const float*)d_in[6];  const float* bUzr = (const float*)d_in[7];
  const float* Wr  = (const float*)d_in[8];  const float* bWr  = (const float*)d_in[9];
  const float* Url = (const float*)d_in[10]; const float* bUrl = (const float*)d_in[11];
  const float* Urr = (const float*)d_in[12]; const float* bUrr = (const float*)d_in[13];
  const float* Wh  = (const float*)d_in[14]; const float* bWh  = (const float*)d_in[15];
  const float* Uhl = (const float*)d_in[16]; const float* bUhl = (const float*)d_in[17];
  const float* Uhr = (const float*)d_in[18]; const float* bUhr = (const float*)d_in[19];

  float* ws = (float*)d_ws;
  float* bc = ws;                              // 384 floats
  float* hA = ws + 1024;                       // NTOK*128 floats (134 MB)
  float* hB = hA + (size_t)NTOK * Hd;          // NTOK/2*128 floats (67 MB)

  bias_combine_k<<<1, 128, 0, stream>>>(bWz,bUzl,bUzr,bWr,bUrl,bUrr,bWh,bUhl,bUhr, bc);

  level0_k<<<NTOK/16, 256, 0, stream>>>(tokens, emb, Wz, Wh, bc, hA);

  // 6 tree levels: n_out = 32,16,8,4,2,1 per batch; M_out = NB * n_out
  const float* src = hA;
  float* other = hB;
  for (int lvl = 1; lvl <= 6; lvl++){
    int lg_nout = 6 - lvl;              // log2(n_out)
    int M = NB << lg_nout;              // output rows
    float* dst = (lvl == 6) ? (float*)d_out : other;
    tree_k<<<M/16, 256, 0, stream>>>(src, dst, lg_nout,
                                     Uzl, Uzr, Url, Urr, Uhl, Uhr, bc);
    other = (float*)src;                // previous src is now free
    src = dst;
  }
}

// Round 4
// 273.044 us; speedup vs baseline: 6.8651x; 6.8651x over previous
//
#include <hip/hip_runtime.h>

// EncoderTreeRNN — f16 MFMA version.
// Level 0: out = (1-z)*tanh(xWh+bh), z = sigm(xWz+bz)   (h=0 kills r and U-terms; zeroed-operand biases still apply)
// Tree:    z = sigm(hl Uzl + hr Uzr + bz), r = sigm(hl Url + hr Urr + br)
//          h~ = tanh((r*hl)Uhl + (r*hr)Uhr + bh), out = z*(hl+hr) + (1-z)*h~
// Tree input rows for output row m are rows 2m,2m+1  ->  A-tile (hl||hr, K=256) is contiguous in hin.

typedef _Float16 half_t;
typedef __attribute__((ext_vector_type(8))) _Float16 f16x8;
typedef __attribute__((ext_vector_type(4))) float f32x4;

#define Hd 128
#define NTOK 262144
#define NB 4096

__device__ __forceinline__ float sigm(float x){ return 1.0f/(1.0f+__expf(-x)); }
__device__ __forceinline__ float tanh_(float x){
  float xc = fminf(fmaxf(x,-15.f),15.f);
  float e = __expf(2.f*xc);
  return (e-1.f)/(e+1.f);
}

// bc[0:128)=bWz+bUzl+bUzr, [128:256)=bWr+bUrl+bUrr, [256:384)=bWh+bUhl+bUhr
__global__ void bias_k(const float* bWz,const float* bUzl,const float* bUzr,
                       const float* bWr,const float* bUrl,const float* bUrr,
                       const float* bWh,const float* bUhl,const float* bUhr, float* bc){
  int j = threadIdx.x;
  if (j < 128)      bc[j] = bWz[j]+bUzl[j]+bUzr[j];
  else if (j < 256){ int i=j-128; bc[j] = bWr[i]+bUrl[i]+bUrr[i]; }
  else if (j < 384){ int i=j-256; bc[j] = bWh[i]+bUhl[i]+bUhr[i]; }
}

// f16 transposed weights: Wt[n][k] = W[k][n]. Concat gates: U*_t is [128][256], k<128 from *l, k>=128 from *r.
__global__ __launch_bounds__(256) void wprep_k(
    const float* Wz, const float* Wh,
    const float* Uzl,const float* Uzr,const float* Url,const float* Urr,
    const float* Uhl,const float* Uhr, half_t* wb){
  int idx = blockIdx.x*256 + threadIdx.x;           // 131072 total
  if (idx < 16384){                                  // Wz_t [128][128]
    int n=idx>>7, k=idx&127; wb[idx] = (half_t)Wz[k*128+n];
  } else if (idx < 32768){                           // Wh_t
    int i=idx-16384; int n=i>>7,k=i&127; wb[idx] = (half_t)Wh[k*128+n];
  } else if (idx < 65536){                           // Uz_t [128][256]
    int i=idx-32768; int n=i>>8,k=i&255;
    wb[idx] = (half_t)(k<128 ? Uzl[k*128+n] : Uzr[(k-128)*128+n]);
  } else if (idx < 98304){                           // Ur_t
    int i=idx-65536; int n=i>>8,k=i&255;
    wb[idx] = (half_t)(k<128 ? Url[k*128+n] : Urr[(k-128)*128+n]);
  } else if (idx < 131072){                          // Uh_t
    int i=idx-98304; int n=i>>8,k=i&255;
    wb[idx] = (half_t)(k<128 ? Uhl[k*128+n] : Uhr[(k-128)*128+n]);
  }
}

// Level 0: 64 rows x 128 cols per block, 4 waves, each wave owns 32 cols. K=128.
__global__ __launch_bounds__(256) void level0_k(
    const int* __restrict__ tokens, const float* __restrict__ emb,
    const half_t* __restrict__ Wz_t, const half_t* __restrict__ Wh_t,
    const float* __restrict__ bc, half_t* __restrict__ hout)
{
  __shared__ __align__(16) _Float16 xs[64][136];   // 272B row stride = 68 dw === 4 mod 32 -> 2-way free
  const int tid = threadIdx.x;
  const int m0  = blockIdx.x*64;
  for (int idx = tid; idx < 64*32; idx += 256){
    int m = idx>>5, c = idx&31;
    int tok = tokens[m0+m];
    float4 v = ((const float4*)(emb + (size_t)tok*128))[c];
    union { half_t h[4]; ushort4 u; } p;
    p.h[0]=(half_t)v.x; p.h[1]=(half_t)v.y; p.h[2]=(half_t)v.z; p.h[3]=(half_t)v.w;
    *(ushort4*)&xs[m][c*4] = p.u;
  }
  __syncthreads();
  const int w = tid>>6, l = tid&63;
  const int lr = l&15, lk = (l>>4)*8, lq = (l>>4)*4;

  f32x4 zacc[4][2] = {}; f32x4 hacc[4][2] = {};
  #pragma unroll
  for (int ks=0; ks<4; ks++){
    f16x8 bz[2], bh[2];
    #pragma unroll
    for (int nt=0; nt<2; nt++){
      int n = w*32 + nt*16 + lr;
      bz[nt] = *(const f16x8*)&Wz_t[n*128 + ks*32 + lk];
      bh[nt] = *(const f16x8*)&Wh_t[n*128 + ks*32 + lk];
    }
    #pragma unroll
    for (int mt=0; mt<4; mt++){
      f16x8 a = *(const f16x8*)&xs[mt*16 + lr][ks*32 + lk];
      #pragma unroll
      for (int nt=0; nt<2; nt++){
        zacc[mt][nt] = __builtin_amdgcn_mfma_f32_16x16x32_f16(a, bz[nt], zacc[mt][nt],0,0,0);
        hacc[mt][nt] = __builtin_amdgcn_mfma_f32_16x16x32_f16(a, bh[nt], hacc[mt][nt],0,0,0);
      }
    }
  }
  #pragma unroll
  for (int nt=0; nt<2; nt++){
    int col = w*32 + nt*16 + lr;
    float bzv = bc[col], bhv = bc[256+col];
    #pragma unroll
    for (int mt=0; mt<4; mt++){
      #pragma unroll
      for (int q=0; q<4; q++){
        int row = mt*16 + lq + q;
        float z  = sigm(zacc[mt][nt][q] + bzv);
        float ht = tanh_(hacc[mt][nt][q] + bhv);
        hout[(size_t)(m0+row)*128 + col] = (half_t)((1.f-z)*ht);
      }
    }
  }
}

// Tree level: 64 out-rows x 128 cols per block, 4 waves x 32 cols. K=256 (hl||hr).
__global__ __launch_bounds__(256) void tree_mfma_k(
    const half_t* __restrict__ hin, half_t* __restrict__ hout, float* __restrict__ outf,
    const half_t* __restrict__ Uz_t, const half_t* __restrict__ Ur_t, const half_t* __restrict__ Uh_t,
    const float* __restrict__ bc, int last)
{
  __shared__ __align__(16) _Float16 xs[64][264];   // 528B row stride = 132 dw === 4 mod 32
  const int tid = threadIdx.x;
  const int m0  = blockIdx.x*64;
  // A-tile = hin rows [2*m0, 2*m0+128) = contiguous 32 KB
  const uint4* src = (const uint4*)(hin + (size_t)m0*256);
  for (int idx = tid; idx < 64*32; idx += 256){
    int m = idx>>5, c = idx&31;
    *(uint4*)&xs[m][c*8] = src[idx];
  }
  __syncthreads();
  const int w = tid>>6, l = tid&63;
  const int lr = l&15, lk = (l>>4)*8, lq = (l>>4)*4;

  // --- z & r GEMMs (shared A) ---
  f32x4 zacc[4][2] = {}; f32x4 racc[4][2] = {};
  #pragma unroll
  for (int ks=0; ks<8; ks++){
    f16x8 bz[2], br[2];
    #pragma unroll
    for (int nt=0; nt<2; nt++){
      int n = w*32 + nt*16 + lr;
      bz[nt] = *(const f16x8*)&Uz_t[n*256 + ks*32 + lk];
      br[nt] = *(const f16x8*)&Ur_t[n*256 + ks*32 + lk];
    }
    #pragma unroll
    for (int mt=0; mt<4; mt++){
      f16x8 a = *(const f16x8*)&xs[mt*16 + lr][ks*32 + lk];
      #pragma unroll
      for (int nt=0; nt<2; nt++){
        zacc[mt][nt] = __builtin_amdgcn_mfma_f32_16x16x32_f16(a, bz[nt], zacc[mt][nt],0,0,0);
        racc[mt][nt] = __builtin_amdgcn_mfma_f32_16x16x32_f16(a, br[nt], racc[mt][nt],0,0,0);
      }
    }
  }
  __syncthreads();   // everyone done reading xs as hl||hr

  // --- elementwise: z, r; overwrite own cols of xs with r*hl / r*hr; keep z and s=hl+hr in regs ---
  float zf[4][2][4], sf[4][2][4];
  #pragma unroll
  for (int nt=0; nt<2; nt++){
    int col = w*32 + nt*16 + lr;
    float bzv = bc[col], brv = bc[128+col];
    #pragma unroll
    for (int mt=0; mt<4; mt++){
      #pragma unroll
      for (int q=0; q<4; q++){
        int row = mt*16 + lq + q;
        float hl = (float)xs[row][col];
        float hr = (float)xs[row][128+col];
        float z  = sigm(zacc[mt][nt][q] + bzv);
        float rv = sigm(racc[mt][nt][q] + brv);
        zf[mt][nt][q] = z;
        sf[mt][nt][q] = hl + hr;
        xs[row][col]     = (half_t)(rv*hl);
        xs[row][128+col] = (half_t)(rv*hr);
      }
    }
  }
  __syncthreads();

  // --- h~ GEMM over (r*hl || r*hr) ---
  f32x4 ha[4][2] = {};
  #pragma unroll
  for (int ks=0; ks<8; ks++){
    f16x8 bh[2];
    #pragma unroll
    for (int nt=0; nt<2; nt++){
      int n = w*32 + nt*16 + lr;
      bh[nt] = *(const f16x8*)&Uh_t[n*256 + ks*32 + lk];
    }
    #pragma unroll
    for (int mt=0; mt<4; mt++){
      f16x8 a = *(const f16x8*)&xs[mt*16 + lr][ks*32 + lk];
      #pragma unroll
      for (int nt=0; nt<2; nt++){
        ha[mt][nt] = __builtin_amdgcn_mfma_f32_16x16x32_f16(a, bh[nt], ha[mt][nt],0,0,0);
      }
    }
  }
  // --- combine + store ---
  #pragma unroll
  for (int nt=0; nt<2; nt++){
    int col = w*32 + nt*16 + lr;
    float bhv = bc[256+col];
    #pragma unroll
    for (int mt=0; mt<4; mt++){
      #pragma unroll
      for (int q=0; q<4; q++){
        int row = mt*16 + lq + q;
        float ht = tanh_(ha[mt][nt][q] + bhv);
        float z  = zf[mt][nt][q];
        float o  = z*sf[mt][nt][q] + (1.f-z)*ht;
        size_t off = (size_t)(m0+row)*128 + col;
        if (last) outf[off] = o;
        else      hout[off] = (half_t)o;
      }
    }
  }
}

extern "C" void kernel_launch(void* const* d_in, const int* in_sizes, int n_in,
                              void* d_out, int out_size, void* d_ws, size_t ws_size,
                              hipStream_t stream) {
  const int*   tokens = (const int*)  d_in[0];
  const float* emb    = (const float*)d_in[1];
  const float* Wz  = (const float*)d_in[2];  const float* bWz  = (const float*)d_in[3];
  const float* Uzl = (const float*)d_in[4];  const float* bUzl = (const float*)d_in[5];
  const float* Uzr = (const float*)d_in[6];  const float* bUzr = (const float*)d_in[7];
  const float* Wr  = (const float*)d_in[8];  const float* bWr  = (const float*)d_in[9];
  const float* Url = (const float*)d_in[10]; const float* bUrl = (const float*)d_in[11];
  const float* Urr = (const float*)d_in[12]; const float* bUrr = (const float*)d_in[13];
  const float* Wh  = (const float*)d_in[14]; const float* bWh  = (const float*)d_in[15];
  const float* Uhl = (const float*)d_in[16]; const float* bUhl = (const float*)d_in[17];
  const float* Uhr = (const float*)d_in[18]; const float* bUhr = (const float*)d_in[19];

  float*  bc = (float*)d_ws;
  half_t* wb = (half_t*)((char*)d_ws + 4096);
  half_t* Wz_t = wb;
  half_t* Wh_t = wb + 16384;
  half_t* Uz_t = wb + 32768;
  half_t* Ur_t = wb + 65536;
  half_t* Uh_t = wb + 98304;
  half_t* hA = (half_t*)((char*)d_ws + (1<<20));     // 262144*128 f16 = 67 MB
  half_t* hB = hA + (size_t)NTOK*128;                // 131072*128 f16 = 33.5 MB

  bias_k<<<1, 384, 0, stream>>>(bWz,bUzl,bUzr,bWr,bUrl,bUrr,bWh,bUhl,bUhr, bc);
  wprep_k<<<512, 256, 0, stream>>>(Wz,Wh,Uzl,Uzr,Url,Urr,Uhl,Uhr, wb);

  level0_k<<<NTOK/64, 256, 0, stream>>>(tokens, emb, Wz_t, Wh_t, bc, hA);

  const half_t* src = hA;
  half_t* other = hB;
  for (int lvl = 1; lvl <= 6; lvl++){
    int M = NB << (6 - lvl);           // 131072 .. 4096 output rows
    int last = (lvl == 6);
    half_t* dst = other;
    tree_mfma_k<<<M/64, 256, 0, stream>>>(src, dst, (float*)d_out,
                                          Uz_t, Ur_t, Uh_t, bc, last);
    other = (half_t*)src;
    src = dst;
  }
}

// Round 5
// 248.814 us; speedup vs baseline: 7.5337x; 1.0974x over previous
//
#include <hip/hip_runtime.h>

// EncoderTreeRNN — f16 MFMA, occupancy-tuned (R5).
// Level 0: h=0 -> z=sigm(xWz+bz), h~=tanh(xWh+bh), out=(1-z)*h~  (r dead; zeroed-operand biases still apply)
// Tree (word=0): z=sigm(hl Uzl+hr Uzr+bz), r=sigm(hl Url+hr Urr+br),
//                h~=tanh((r*hl)Uhl+(r*hr)Uhr+bh), out=z*(hl+hr)+(1-z)*h~
// Wave layout: 512 thr = 8 waves, wave w owns 16 output cols [16w,16w+16); mt=4 row-tiles (64 rows/block).
// This halves AGPR vs R4 (acc per wave: 4 tiles/gemm) -> target ~95 regs -> 4-5 waves/SIMD.

typedef _Float16 half_t;
typedef __attribute__((ext_vector_type(8))) _Float16 f16x8;
typedef __attribute__((ext_vector_type(4))) float f32x4;

#define NTOK 262144
#define NB 4096

__device__ __forceinline__ float sigm(float x){ return 1.0f/(1.0f+__expf(-x)); }
__device__ __forceinline__ float tanh_(float x){
  float xc = fminf(fmaxf(x,-15.f),15.f);
  float e = __expf(2.f*xc);
  return (e-1.f)/(e+1.f);
}

// bc[0:128)=bWz+bUzl+bUzr, [128:256)=bWr+bUrl+bUrr, [256:384)=bWh+bUhl+bUhr
__global__ void bias_k(const float* bWz,const float* bUzl,const float* bUzr,
                       const float* bWr,const float* bUrl,const float* bUrr,
                       const float* bWh,const float* bUhl,const float* bUhr, float* bc){
  int j = threadIdx.x;
  if (j < 128)      bc[j] = bWz[j]+bUzl[j]+bUzr[j];
  else if (j < 256){ int i=j-128; bc[j] = bWr[i]+bUrl[i]+bUrr[i]; }
  else if (j < 384){ int i=j-256; bc[j] = bWh[i]+bUhl[i]+bUhr[i]; }
}

// f16 transposed weights Wt[n][k]=W[k][n]; U*_t is [128][256] with k<128 from *l, k>=128 from *r.
__global__ __launch_bounds__(256) void wprep_k(
    const float* Wz, const float* Wh,
    const float* Uzl,const float* Uzr,const float* Url,const float* Urr,
    const float* Uhl,const float* Uhr, half_t* wb){
  int idx = blockIdx.x*256 + threadIdx.x;           // 131072 total
  if (idx < 16384){
    int n=idx>>7, k=idx&127; wb[idx] = (half_t)Wz[k*128+n];
  } else if (idx < 32768){
    int i=idx-16384; int n=i>>7,k=i&127; wb[idx] = (half_t)Wh[k*128+n];
  } else if (idx < 65536){
    int i=idx-32768; int n=i>>8,k=i&255;
    wb[idx] = (half_t)(k<128 ? Uzl[k*128+n] : Uzr[(k-128)*128+n]);
  } else if (idx < 98304){
    int i=idx-65536; int n=i>>8,k=i&255;
    wb[idx] = (half_t)(k<128 ? Url[k*128+n] : Urr[(k-128)*128+n]);
  } else if (idx < 131072){
    int i=idx-98304; int n=i>>8,k=i&255;
    wb[idx] = (half_t)(k<128 ? Uhl[k*128+n] : Uhr[(k-128)*128+n]);
  }
}

// Level 0: 64 rows x 128 cols per block, 8 waves x 16 cols, mt=4. K=128.
__global__ __launch_bounds__(512, 4) void level0_k(
    const int* __restrict__ tokens, const float* __restrict__ emb,
    const half_t* __restrict__ Wz_t, const half_t* __restrict__ Wh_t,
    const float* __restrict__ bc, half_t* __restrict__ hout)
{
  __shared__ __align__(16) _Float16 xs[64][136];   // 272B stride = 68 dw === 4 mod 32 -> min-phase b128
  const int tid = threadIdx.x;
  const int m0  = blockIdx.x*64;
  for (int idx = tid; idx < 64*32; idx += 512){
    int m = idx>>5, c = idx&31;
    int tok = tokens[m0+m];
    float4 v = ((const float4*)(emb + (size_t)tok*128))[c];
    union { half_t h[4]; ushort4 u; } p;
    p.h[0]=(half_t)v.x; p.h[1]=(half_t)v.y; p.h[2]=(half_t)v.z; p.h[3]=(half_t)v.w;
    *(ushort4*)&xs[m][c*4] = p.u;
  }
  __syncthreads();
  const int w = tid>>6, l = tid&63;
  const int lr = l&15, lk = (l>>4)*8, lq = (l>>4)*4;
  const int col = w*16 + lr;

  f32x4 zacc[4] = {}; f32x4 hacc[4] = {};
  f16x8 bz_n = *(const f16x8*)&Wz_t[col*128 + lk];
  f16x8 bh_n = *(const f16x8*)&Wh_t[col*128 + lk];
  #pragma unroll
  for (int ks=0; ks<4; ks++){
    f16x8 bz = bz_n, bh = bh_n;
    if (ks < 3){
      bz_n = *(const f16x8*)&Wz_t[col*128 + (ks+1)*32 + lk];
      bh_n = *(const f16x8*)&Wh_t[col*128 + (ks+1)*32 + lk];
    }
    #pragma unroll
    for (int mt=0; mt<4; mt++){
      f16x8 a = *(const f16x8*)&xs[mt*16 + lr][ks*32 + lk];
      zacc[mt] = __builtin_amdgcn_mfma_f32_16x16x32_f16(a, bz, zacc[mt],0,0,0);
      hacc[mt] = __builtin_amdgcn_mfma_f32_16x16x32_f16(a, bh, hacc[mt],0,0,0);
    }
  }
  const float bzv = bc[col], bhv = bc[256+col];
  #pragma unroll
  for (int mt=0; mt<4; mt++){
    #pragma unroll
    for (int q=0; q<4; q++){
      int row = mt*16 + lq + q;
      float z  = sigm(zacc[mt][q] + bzv);
      float ht = tanh_(hacc[mt][q] + bhv);
      hout[(size_t)(m0+row)*128 + col] = (half_t)((1.f-z)*ht);
    }
  }
}

// Tree level: 64 out-rows x 128 cols per block, 8 waves x 16 cols, mt=4. K=256 (hl||hr contiguous in hin).
__global__ __launch_bounds__(512, 4) void tree_k(
    const half_t* __restrict__ hin, half_t* __restrict__ hout, float* __restrict__ outf,
    const half_t* __restrict__ Uz_t, const half_t* __restrict__ Ur_t, const half_t* __restrict__ Uh_t,
    const float* __restrict__ bc, int last)
{
  __shared__ __align__(16) _Float16 xs[64][264];   // 528B stride = 132 dw === 4 mod 32 -> min-phase b128
  const int tid = threadIdx.x;
  const int m0  = blockIdx.x*64;
  const uint4* src = (const uint4*)(hin + (size_t)m0*256);   // A-tile: 32 KB contiguous
  for (int idx = tid; idx < 64*32; idx += 512){
    int m = idx>>5, c = idx&31;
    *(uint4*)&xs[m][c*8] = src[idx];
  }
  __syncthreads();
  const int w = tid>>6, l = tid&63;
  const int lr = l&15, lk = (l>>4)*8, lq = (l>>4)*4;
  const int col = w*16 + lr;

  // --- z & r GEMMs (shared A-frags) ---
  f32x4 zacc[4] = {}; f32x4 racc[4] = {};
  f16x8 bz_n = *(const f16x8*)&Uz_t[col*256 + lk];
  f16x8 br_n = *(const f16x8*)&Ur_t[col*256 + lk];
  #pragma unroll
  for (int ks=0; ks<8; ks++){
    f16x8 bz = bz_n, br = br_n;
    if (ks < 7){
      bz_n = *(const f16x8*)&Uz_t[col*256 + (ks+1)*32 + lk];
      br_n = *(const f16x8*)&Ur_t[col*256 + (ks+1)*32 + lk];
    }
    #pragma unroll
    for (int mt=0; mt<4; mt++){
      f16x8 a = *(const f16x8*)&xs[mt*16 + lr][ks*32 + lk];
      zacc[mt] = __builtin_amdgcn_mfma_f32_16x16x32_f16(a, bz, zacc[mt],0,0,0);
      racc[mt] = __builtin_amdgcn_mfma_f32_16x16x32_f16(a, br, racc[mt],0,0,0);
    }
  }
  __syncthreads();   // all A-frag reads of raw h done

  // --- elementwise: z, r; overwrite own elements with r*hl / r*hr; keep z, s=hl+hr in regs ---
  float zf[4][4], sf[4][4];
  const float bzv = bc[col], brv = bc[128+col];
  #pragma unroll
  for (int mt=0; mt<4; mt++){
    #pragma unroll
    for (int q=0; q<4; q++){
      int row = mt*16 + lq + q;
      float hl = (float)xs[row][col];
      float hr = (float)xs[row][128+col];
      float z  = sigm(zacc[mt][q] + bzv);
      float rv = sigm(racc[mt][q] + brv);
      zf[mt][q] = z;
      sf[mt][q] = hl + hr;
      xs[row][col]     = (half_t)(rv*hl);
      xs[row][128+col] = (half_t)(rv*hr);
    }
  }
  __syncthreads();

  // --- h~ GEMM over (r*hl || r*hr) ---
  f32x4 ha[4] = {};
  f16x8 bh_n = *(const f16x8*)&Uh_t[col*256 + lk];
  #pragma unroll
  for (int ks=0; ks<8; ks++){
    f16x8 bh = bh_n;
    if (ks < 7) bh_n = *(const f16x8*)&Uh_t[col*256 + (ks+1)*32 + lk];
    #pragma unroll
    for (int mt=0; mt<4; mt++){
      f16x8 a = *(const f16x8*)&xs[mt*16 + lr][ks*32 + lk];
      ha[mt] = __builtin_amdgcn_mfma_f32_16x16x32_f16(a, bh, ha[mt],0,0,0);
    }
  }
  // --- combine + store ---
  const float bhv = bc[256+col];
  #pragma unroll
  for (int mt=0; mt<4; mt++){
    #pragma unroll
    for (int q=0; q<4; q++){
      int row = mt*16 + lq + q;
      float ht = tanh_(ha[mt][q] + bhv);
      float z  = zf[mt][q];
      float o  = z*sf[mt][q] + (1.f-z)*ht;
      size_t off = (size_t)(m0+row)*128 + col;
      if (last) outf[off] = o;
      else      hout[off] = (half_t)o;
    }
  }
}

extern "C" void kernel_launch(void* const* d_in, const int* in_sizes, int n_in,
                              void* d_out, int out_size, void* d_ws, size_t ws_size,
                              hipStream_t stream) {
  const int*   tokens = (const int*)  d_in[0];
  const float* emb    = (const float*)d_in[1];
  const float* Wz  = (const float*)d_in[2];  const float* bWz  = (const float*)d_in[3];
  const float* Uzl = (const float*)d_in[4];  const float* bUzl = (const float*)d_in[5];
  const float* Uzr = (const float*)d_in[6];  const float* bUzr = (const float*)d_in[7];
  const float* Wr  = (const float*)d_in[8];  const float* bWr  = (const float*)d_in[9];
  const float* Url = (const float*)d_in[10]; const float* bUrl = (const float*)d_in[11];
  const float* Urr = (const float*)d_in[12]; const float* bUrr = (const float*)d_in[13];
  const float* Wh  = (const float*)d_in[14]; const float* bWh  = (const float*)d_in[15];
  const float* Uhl = (const float*)d_in[16]; const float* bUhl = (const float*)d_in[17];
  const float* Uhr = (const float*)d_in[18]; const float* bUhr = (const float*)d_in[19];

  float*  bc = (float*)d_ws;
  half_t* wb = (half_t*)((char*)d_ws + 4096);
  half_t* Wz_t = wb;
  half_t* Wh_t = wb + 16384;
  half_t* Uz_t = wb + 32768;
  half_t* Ur_t = wb + 65536;
  half_t* Uh_t = wb + 98304;
  half_t* hA = (half_t*)((char*)d_ws + (1<<20));     // 262144*128 f16 = 67 MB
  half_t* hB = hA + (size_t)NTOK*128;                // 131072*128 f16 = 33.5 MB

  bias_k<<<1, 384, 0, stream>>>(bWz,bUzl,bUzr,bWr,bUrl,bUrr,bWh,bUhl,bUhr, bc);
  wprep_k<<<512, 256, 0, stream>>>(Wz,Wh,Uzl,Uzr,Url,Urr,Uhl,Uhr, wb);

  level0_k<<<NTOK/64, 512, 0, stream>>>(tokens, emb, Wz_t, Wh_t, bc, hA);

  const half_t* src = hA;
  half_t* other = hB;
  for (int lvl = 1; lvl <= 6; lvl++){
    int M = NB << (6 - lvl);           // 131072 .. 4096 output rows
    int last = (lvl == 6);
    half_t* dst = other;
    tree_k<<<M/64, 512, 0, stream>>>(src, dst, (float*)d_out,
                                     Uz_t, Ur_t, Uh_t, bc, last);
    other = (half_t*)src;
    src = dst;
  }
}

// Round 6
// 235.460 us; speedup vs baseline: 7.9609x; 1.0567x over previous
//
#include <hip/hip_runtime.h>

// EncoderTreeRNN — f16 MFMA, R6: MT=8 row-tiles (128 rows/block) to amortize B-loads & barriers.
// Level 0: h=0 -> z=sigm(xWz+bz), h~=tanh(xWh+bh), out=(1-z)*h~  (r dead; zeroed-operand biases apply)
// Tree (word=0): z=sigm(hl Uzl+hr Uzr+bz), r=sigm(hl Url+hr Urr+br),
//                h~=tanh((r*hl)Uhl+(r*hr)Uhr+bh), out=z*(hl+hr)+(1-z)*h~
// 512 thr = 8 waves; wave w owns cols [16w,16w+16). A-tile (hl||hr, K=256) contiguous in hin.

typedef _Float16 half_t;
typedef __attribute__((ext_vector_type(8))) _Float16 f16x8;
typedef __attribute__((ext_vector_type(4))) float f32x4;

#define NTOK 262144
#define NB 4096

__device__ __forceinline__ float sigm(float x){ return 1.0f/(1.0f+__expf(-x)); }
__device__ __forceinline__ float tanh_(float x){
  float xc = fminf(fmaxf(x,-15.f),15.f);
  float e = __expf(2.f*xc);
  return (e-1.f)/(e+1.f);
}

// bc[0:128)=bWz+bUzl+bUzr, [128:256)=bWr+bUrl+bUrr, [256:384)=bWh+bUhl+bUhr
__global__ void bias_k(const float* bWz,const float* bUzl,const float* bUzr,
                       const float* bWr,const float* bUrl,const float* bUrr,
                       const float* bWh,const float* bUhl,const float* bUhr, float* bc){
  int j = threadIdx.x;
  if (j < 128)      bc[j] = bWz[j]+bUzl[j]+bUzr[j];
  else if (j < 256){ int i=j-128; bc[j] = bWr[i]+bUrl[i]+bUrr[i]; }
  else if (j < 384){ int i=j-256; bc[j] = bWh[i]+bUhl[i]+bUhr[i]; }
}

// f16 transposed weights Wt[n][k]=W[k][n]; U*_t is [128][256] with k<128 from *l, k>=128 from *r.
__global__ __launch_bounds__(256) void wprep_k(
    const float* Wz, const float* Wh,
    const float* Uzl,const float* Uzr,const float* Url,const float* Urr,
    const float* Uhl,const float* Uhr, half_t* wb){
  int idx = blockIdx.x*256 + threadIdx.x;           // 131072 total
  if (idx < 16384){
    int n=idx>>7, k=idx&127; wb[idx] = (half_t)Wz[k*128+n];
  } else if (idx < 32768){
    int i=idx-16384; int n=i>>7,k=i&127; wb[idx] = (half_t)Wh[k*128+n];
  } else if (idx < 65536){
    int i=idx-32768; int n=i>>8,k=i&255;
    wb[idx] = (half_t)(k<128 ? Uzl[k*128+n] : Uzr[(k-128)*128+n]);
  } else if (idx < 98304){
    int i=idx-65536; int n=i>>8,k=i&255;
    wb[idx] = (half_t)(k<128 ? Url[k*128+n] : Urr[(k-128)*128+n]);
  } else if (idx < 131072){
    int i=idx-98304; int n=i>>8,k=i&255;
    wb[idx] = (half_t)(k<128 ? Uhl[k*128+n] : Uhr[(k-128)*128+n]);
  }
}

// Level 0: MT*16 rows x 128 cols per block, 8 waves x 16 cols. K=128.
template<int MT>
__global__ __launch_bounds__(512, 4) void level0_k(
    const int* __restrict__ tokens, const float* __restrict__ emb,
    const half_t* __restrict__ Wz_t, const half_t* __restrict__ Wh_t,
    const float* __restrict__ bc, half_t* __restrict__ hout)
{
  __shared__ __align__(16) _Float16 xs[MT*16][136];   // 272B stride === 4 dw mod 32 -> min-phase b128
  const int tid = threadIdx.x;
  const int m0  = blockIdx.x*(MT*16);
  #pragma unroll
  for (int it = 0; it < MT; it++){
    int idx = it*512 + tid;                // MT*16*32 float4-chunks
    int m = idx>>5, c = idx&31;
    int tok = tokens[m0+m];
    float4 v = ((const float4*)(emb + (size_t)tok*128))[c];
    union { half_t h[4]; ushort4 u; } p;
    p.h[0]=(half_t)v.x; p.h[1]=(half_t)v.y; p.h[2]=(half_t)v.z; p.h[3]=(half_t)v.w;
    *(ushort4*)&xs[m][c*4] = p.u;
  }
  __syncthreads();
  const int w = tid>>6, l = tid&63;
  const int lr = l&15, lk = (l>>4)*8, lq = (l>>4)*4;
  const int col = w*16 + lr;

  f32x4 zacc[MT] = {}; f32x4 hacc[MT] = {};
  f16x8 bz_n = *(const f16x8*)&Wz_t[col*128 + lk];
  f16x8 bh_n = *(const f16x8*)&Wh_t[col*128 + lk];
  #pragma unroll
  for (int ks=0; ks<4; ks++){
    f16x8 bz = bz_n, bh = bh_n;
    if (ks < 3){
      bz_n = *(const f16x8*)&Wz_t[col*128 + (ks+1)*32 + lk];
      bh_n = *(const f16x8*)&Wh_t[col*128 + (ks+1)*32 + lk];
    }
    #pragma unroll
    for (int mt=0; mt<MT; mt++){
      f16x8 a = *(const f16x8*)&xs[mt*16 + lr][ks*32 + lk];
      zacc[mt] = __builtin_amdgcn_mfma_f32_16x16x32_f16(a, bz, zacc[mt],0,0,0);
      hacc[mt] = __builtin_amdgcn_mfma_f32_16x16x32_f16(a, bh, hacc[mt],0,0,0);
    }
  }
  const float bzv = bc[col], bhv = bc[256+col];
  #pragma unroll
  for (int mt=0; mt<MT; mt++){
    #pragma unroll
    for (int q=0; q<4; q++){
      int row = mt*16 + lq + q;
      float z  = sigm(zacc[mt][q] + bzv);
      float ht = tanh_(hacc[mt][q] + bhv);
      hout[(size_t)(m0+row)*128 + col] = (half_t)((1.f-z)*ht);
    }
  }
}

// Tree level: MT*16 out-rows x 128 cols per block, 8 waves x 16 cols. K=256 (hl||hr contiguous).
template<int MT>
__global__ __launch_bounds__(512, 4) void tree_k(
    const half_t* __restrict__ hin, half_t* __restrict__ hout, float* __restrict__ outf,
    const half_t* __restrict__ Uz_t, const half_t* __restrict__ Ur_t, const half_t* __restrict__ Uh_t,
    const float* __restrict__ bc, int last)
{
  __shared__ __align__(16) _Float16 xs[MT*16][264];   // 528B stride === 4 dw mod 32 -> min-phase b128
  const int tid = threadIdx.x;
  const int m0  = blockIdx.x*(MT*16);
  const uint4* src = (const uint4*)(hin + (size_t)m0*256);   // A-tile: MT*16 rows x 256 halves, contiguous
  #pragma unroll
  for (int it = 0; it < MT; it++){
    int idx = it*512 + tid;
    int m = idx>>5, c = idx&31;
    *(uint4*)&xs[m][c*8] = src[idx];
  }
  __syncthreads();
  const int w = tid>>6, l = tid&63;
  const int lr = l&15, lk = (l>>4)*8, lq = (l>>4)*4;
  const int col = w*16 + lr;

  // --- z & r GEMMs (shared A-frags) ---
  f32x4 zacc[MT] = {}; f32x4 racc[MT] = {};
  f16x8 bz_n = *(const f16x8*)&Uz_t[col*256 + lk];
  f16x8 br_n = *(const f16x8*)&Ur_t[col*256 + lk];
  #pragma unroll
  for (int ks=0; ks<8; ks++){
    f16x8 bz = bz_n, br = br_n;
    if (ks < 7){
      bz_n = *(const f16x8*)&Uz_t[col*256 + (ks+1)*32 + lk];
      br_n = *(const f16x8*)&Ur_t[col*256 + (ks+1)*32 + lk];
    }
    #pragma unroll
    for (int mt=0; mt<MT; mt++){
      f16x8 a = *(const f16x8*)&xs[mt*16 + lr][ks*32 + lk];
      zacc[mt] = __builtin_amdgcn_mfma_f32_16x16x32_f16(a, bz, zacc[mt],0,0,0);
      racc[mt] = __builtin_amdgcn_mfma_f32_16x16x32_f16(a, br, racc[mt],0,0,0);
    }
  }
  __syncthreads();   // all reads of raw h done

  // --- elementwise: z,r; overwrite own elements with r*hl / r*hr; carry z, s=hl+hr packed f16 ---
  uint zp[MT][2], sp[MT][2];
  const float bzv = bc[col], brv = bc[128+col];
  #pragma unroll
  for (int mt=0; mt<MT; mt++){
    union { half_t h[4]; uint u[2]; } pz, ps;
    #pragma unroll
    for (int q=0; q<4; q++){
      int row = mt*16 + lq + q;
      float hl = (float)xs[row][col];
      float hr = (float)xs[row][128+col];
      float z  = sigm(zacc[mt][q] + bzv);
      float rv = sigm(racc[mt][q] + brv);
      pz.h[q] = (half_t)z;
      ps.h[q] = (half_t)(hl + hr);
      xs[row][col]     = (half_t)(rv*hl);
      xs[row][128+col] = (half_t)(rv*hr);
    }
    zp[mt][0]=pz.u[0]; zp[mt][1]=pz.u[1];
    sp[mt][0]=ps.u[0]; sp[mt][1]=ps.u[1];
  }
  __syncthreads();

  // --- h~ GEMM over (r*hl || r*hr) ---
  f32x4 ha[MT] = {};
  f16x8 bh_n = *(const f16x8*)&Uh_t[col*256 + lk];
  #pragma unroll
  for (int ks=0; ks<8; ks++){
    f16x8 bh = bh_n;
    if (ks < 7) bh_n = *(const f16x8*)&Uh_t[col*256 + (ks+1)*32 + lk];
    #pragma unroll
    for (int mt=0; mt<MT; mt++){
      f16x8 a = *(const f16x8*)&xs[mt*16 + lr][ks*32 + lk];
      ha[mt] = __builtin_amdgcn_mfma_f32_16x16x32_f16(a, bh, ha[mt],0,0,0);
    }
  }
  // --- combine + store ---
  const float bhv = bc[256+col];
  #pragma unroll
  for (int mt=0; mt<MT; mt++){
    union { half_t h[4]; uint u[2]; } pz, ps;
    pz.u[0]=zp[mt][0]; pz.u[1]=zp[mt][1];
    ps.u[0]=sp[mt][0]; ps.u[1]=sp[mt][1];
    #pragma unroll
    for (int q=0; q<4; q++){
      int row = mt*16 + lq + q;
      float ht = tanh_(ha[mt][q] + bhv);
      float z  = (float)pz.h[q];
      float o  = z*(float)ps.h[q] + (1.f-z)*ht;
      size_t off = (size_t)(m0+row)*128 + col;
      if (last) outf[off] = o;
      else      hout[off] = (half_t)o;
    }
  }
}

extern "C" void kernel_launch(void* const* d_in, const int* in_sizes, int n_in,
                              void* d_out, int out_size, void* d_ws, size_t ws_size,
                              hipStream_t stream) {
  const int*   tokens = (const int*)  d_in[0];
  const float* emb    = (const float*)d_in[1];
  const float* Wz  = (const float*)d_in[2];  const float* bWz  = (const float*)d_in[3];
  const float* Uzl = (const float*)d_in[4];  const float* bUzl = (const float*)d_in[5];
  const float* Uzr = (const float*)d_in[6];  const float* bUzr = (const float*)d_in[7];
  const float* Wr  = (const float*)d_in[8];  const float* bWr  = (const float*)d_in[9];
  const float* Url = (const float*)d_in[10]; const float* bUrl = (const float*)d_in[11];
  const float* Urr = (const float*)d_in[12]; const float* bUrr = (const float*)d_in[13];
  const float* Wh  = (const float*)d_in[14]; const float* bWh  = (const float*)d_in[15];
  const float* Uhl = (const float*)d_in[16]; const float* bUhl = (const float*)d_in[17];
  const float* Uhr = (const float*)d_in[18]; const float* bUhr = (const float*)d_in[19];

  float*  bc = (float*)d_ws;
  half_t* wb = (half_t*)((char*)d_ws + 4096);
  half_t* Wz_t = wb;
  half_t* Wh_t = wb + 16384;
  half_t* Uz_t = wb + 32768;
  half_t* Ur_t = wb + 65536;
  half_t* Uh_t = wb + 98304;
  half_t* hA = (half_t*)((char*)d_ws + (1<<20));     // 262144*128 f16 = 67 MB
  half_t* hB = hA + (size_t)NTOK*128;                // 131072*128 f16 = 33.5 MB

  bias_k<<<1, 384, 0, stream>>>(bWz,bUzl,bUzr,bWr,bUrl,bUrr,bWh,bUhl,bUhr, bc);
  wprep_k<<<512, 256, 0, stream>>>(Wz,Wh,Uzl,Uzr,Url,Urr,Uhl,Uhr, wb);

  level0_k<8><<<NTOK/128, 512, 0, stream>>>(tokens, emb, Wz_t, Wh_t, bc, hA);

  const half_t* src = hA;
  half_t* other = hB;
  for (int lvl = 1; lvl <= 6; lvl++){
    int M = NB << (6 - lvl);           // 131072 .. 4096 output rows
    int last = (lvl == 6);
    half_t* dst = other;
    if (M >= 32768){
      tree_k<8><<<M/128, 512, 0, stream>>>(src, dst, (float*)d_out,
                                           Uz_t, Ur_t, Uh_t, bc, last);
    } else {
      tree_k<4><<<M/64, 512, 0, stream>>>(src, dst, (float*)d_out,
                                          Uz_t, Ur_t, Uh_t, bc, last);
    }
    other = (half_t*)src;
    src = dst;
  }
}

// Round 7
// 168.807 us; speedup vs baseline: 11.1043x; 1.3948x over previous
//
#include <hip/hip_runtime.h>

// EncoderTreeRNN — f16 MFMA, R7: coalesced fragment-layout weights, interleaved hl/hr LDS,
// rcp-based activations.
// Level 0: h=0 -> z=sigm(xWz+bz), h~=tanh(xWh+bh), out=(1-z)*h~
// Tree (word=0): z=sigm(hl Uzl+hr Uzr+bz), r=sigm(hl Url+hr Urr+br),
//                h~=tanh((r*hl)Uhl+(r*hr)Uhr+bh), out=z*(hl+hr)+(1-z)*h~
// K-dim of tree GEMMs is PERMUTED: k'=2j -> hl[j], k'=2j+1 -> hr[j]; U rows permuted to match
// (sum over k unchanged). LDS stores {hl[j],hr[j]} adjacent -> elementwise is 1 b32 read + 1 b32 write.
// Weights stored fragment-contiguous: frag(w,ks) = 64 lanes x 16B contiguous -> coalesced B-loads.

typedef _Float16 half_t;
typedef __attribute__((ext_vector_type(8))) _Float16 f16x8;
typedef __attribute__((ext_vector_type(4))) float f32x4;

#define NTOK 262144
#define NB 4096

__device__ __forceinline__ float sigm(float x){
  float e = __expf(-x);
  return __builtin_amdgcn_rcpf(1.0f + e);
}
__device__ __forceinline__ float tanh_(float x){
  float xc = fminf(fmaxf(x,-15.f),15.f);
  float e = __expf(2.f*xc);
  return (e - 1.f) * __builtin_amdgcn_rcpf(e + 1.f);
}

// bc[0:128)=bWz+bUzl+bUzr, [128:256)=bWr+bUrl+bUrr, [256:384)=bWh+bUhl+bUhr
__global__ void bias_k(const float* bWz,const float* bUzl,const float* bUzr,
                       const float* bWr,const float* bUrl,const float* bUrr,
                       const float* bWh,const float* bUhl,const float* bUhr, float* bc){
  int j = threadIdx.x;
  if (j < 128)      bc[j] = bWz[j]+bUzl[j]+bUzr[j];
  else if (j < 256){ int i=j-128; bc[j] = bWr[i]+bUrl[i]+bUrr[i]; }
  else if (j < 384){ int i=j-256; bc[j] = bWh[i]+bUhl[i]+bUhr[i]; }
}

// Fragment-contiguous weights.
// W (K=128): Wf[((w*4+ks)*64+l)*8+j]  = W[k][n], n=w*16+(l&15), k=ks*32+(l>>4)*8+j.   16384 halves each.
// U (K=256, interleaved k'): Uf[((w*8+ks)*64+l)*8+j] = U'{k'}[n], k'=ks*32+(l>>4)*8+j,
//   k' even -> Ul[k'/2][n], odd -> Ur[k'/2][n]; n=w*16+(l&15).                        32768 halves each.
__global__ __launch_bounds__(256) void wprep_k(
    const float* Wz, const float* Wh,
    const float* Uzl,const float* Uzr,const float* Url,const float* Urr,
    const float* Uhl,const float* Uhr, half_t* wb){
  int idx = blockIdx.x*256 + threadIdx.x;           // 131072 total
  if (idx < 32768){                                  // Wz_f, Wh_f
    const float* W = (idx < 16384) ? Wz : Wh;
    int t = idx & 16383;
    int w = t >> 11, ks = (t >> 9) & 3, l = (t >> 3) & 63, j = t & 7;
    int n = w*16 + (l & 15);
    int k = ks*32 + ((l >> 4) << 3) + j;
    wb[idx] = (half_t)W[k*128 + n];
  } else {                                           // Uz_f, Ur_f, Uh_f
    int t = idx - 32768;
    int mat = t >> 15;                               // 0=z,1=r,2=h
    t &= 32767;
    int w = t >> 12, ks = (t >> 9) & 7, l = (t >> 3) & 63, j = t & 7;
    int n = w*16 + (l & 15);
    int kp = ks*32 + ((l >> 4) << 3) + j;            // 0..255 interleaved
    int k = kp >> 1;
    const float* U;
    if (mat == 0) U = (kp & 1) ? Uzr : Uzl;
    else if (mat == 1) U = (kp & 1) ? Urr : Url;
    else U = (kp & 1) ? Uhr : Uhl;
    wb[idx] = (half_t)U[k*128 + n];
  }
}

// Level 0: MT*16 rows x 128 cols per block, 8 waves x 16 cols. K=128.
template<int MT>
__global__ __launch_bounds__(512, 4) void level0_k(
    const int* __restrict__ tokens, const float* __restrict__ emb,
    const half_t* __restrict__ Wz_f, const half_t* __restrict__ Wh_f,
    const float* __restrict__ bc, half_t* __restrict__ hout)
{
  __shared__ __align__(16) _Float16 xs[MT*16][136];   // 272B stride === 4 dw mod 32
  const int tid = threadIdx.x;
  const int m0  = blockIdx.x*(MT*16);
  #pragma unroll
  for (int it = 0; it < MT; it++){
    int idx = it*512 + tid;                // MT*16 rows x 32 float4-chunks
    int m = idx >> 5, c = idx & 31;
    int tok = tokens[m0+m];
    float4 v = ((const float4*)(emb + (size_t)tok*128))[c];
    union { half_t h[4]; ushort4 u; } p;
    p.h[0]=(half_t)v.x; p.h[1]=(half_t)v.y; p.h[2]=(half_t)v.z; p.h[3]=(half_t)v.w;
    *(ushort4*)&xs[m][c*4] = p.u;
  }
  __syncthreads();
  const int w = tid>>6, l = tid&63;
  const int lr = l&15, lk = (l>>4)*8, lq = (l>>4)*4;
  const int col = w*16 + lr;

  f32x4 zacc[MT] = {}; f32x4 hacc[MT] = {};
  const half_t* wzp = Wz_f + ((w*4)*64 + l)*8;
  const half_t* whp = Wh_f + ((w*4)*64 + l)*8;
  f16x8 bz_n = *(const f16x8*)wzp;
  f16x8 bh_n = *(const f16x8*)whp;
  #pragma unroll
  for (int ks=0; ks<4; ks++){
    f16x8 bz = bz_n, bh = bh_n;
    if (ks < 3){
      bz_n = *(const f16x8*)(wzp + (ks+1)*512);
      bh_n = *(const f16x8*)(whp + (ks+1)*512);
    }
    #pragma unroll
    for (int mt=0; mt<MT; mt++){
      f16x8 a = *(const f16x8*)&xs[mt*16 + lr][ks*32 + lk];
      zacc[mt] = __builtin_amdgcn_mfma_f32_16x16x32_f16(a, bz, zacc[mt],0,0,0);
      hacc[mt] = __builtin_amdgcn_mfma_f32_16x16x32_f16(a, bh, hacc[mt],0,0,0);
    }
  }
  const float bzv = bc[col], bhv = bc[256+col];
  #pragma unroll
  for (int mt=0; mt<MT; mt++){
    #pragma unroll
    for (int q=0; q<4; q++){
      int row = mt*16 + lq + q;
      float z  = sigm(zacc[mt][q] + bzv);
      float ht = tanh_(hacc[mt][q] + bhv);
      hout[(size_t)(m0+row)*128 + col] = (half_t)((1.f-z)*ht);
    }
  }
}

// Tree level: MT*16 out-rows x 128 cols per block, 8 waves x 16 cols. K=256 interleaved.
template<int MT>
__global__ __launch_bounds__(512, 4) void tree_k(
    const half_t* __restrict__ hin, half_t* __restrict__ hout, float* __restrict__ outf,
    const half_t* __restrict__ Uz_f, const half_t* __restrict__ Ur_f, const half_t* __restrict__ Uh_f,
    const float* __restrict__ bc, int last)
{
  __shared__ __align__(16) _Float16 xs[MT*16][264];   // 528B stride === 4 dw mod 32
  const int tid = threadIdx.x;
  const int m0  = blockIdx.x*(MT*16);
  // stage interleaved: xs[m][2j]=hl[m][j]=hin[2(m0+m)][j], xs[m][2j+1]=hr[m][j]=hin[2(m0+m)+1][j]
  #pragma unroll
  for (int it = 0; it < MT; it++){
    int idx = it*512 + tid;                 // MT*16 rows x 32 chunks (4 j-pairs each)
    int m = idx >> 5, c = idx & 31;
    size_t base = (size_t)(2*(m0+m))*128 + c*4;
    uint2 A  = *(const uint2*)(hin + base);        // hl[j0..j0+3]
    uint2 Bv = *(const uint2*)(hin + base + 128);  // hr[j0..j0+3]
    uint4 o;
    o.x = (A.x & 0xFFFFu) | (Bv.x << 16);
    o.y = (A.x >> 16)     | (Bv.x & 0xFFFF0000u);
    o.z = (A.y & 0xFFFFu) | (Bv.y << 16);
    o.w = (A.y >> 16)     | (Bv.y & 0xFFFF0000u);
    *(uint4*)&xs[m][c*8] = o;
  }
  __syncthreads();
  const int w = tid>>6, l = tid&63;
  const int lr = l&15, lk = (l>>4)*8, lq = (l>>4)*4;
  const int col = w*16 + lr;

  // --- z & r GEMMs (shared A-frags, coalesced frag-layout B) ---
  f32x4 zacc[MT] = {}; f32x4 racc[MT] = {};
  const half_t* uzp = Uz_f + ((w*8)*64 + l)*8;
  const half_t* urp = Ur_f + ((w*8)*64 + l)*8;
  f16x8 bz_n = *(const f16x8*)uzp;
  f16x8 br_n = *(const f16x8*)urp;
  #pragma unroll
  for (int ks=0; ks<8; ks++){
    f16x8 bz = bz_n, br = br_n;
    if (ks < 7){
      bz_n = *(const f16x8*)(uzp + (ks+1)*512);
      br_n = *(const f16x8*)(urp + (ks+1)*512);
    }
    #pragma unroll
    for (int mt=0; mt<MT; mt++){
      f16x8 a = *(const f16x8*)&xs[mt*16 + lr][ks*32 + lk];
      zacc[mt] = __builtin_amdgcn_mfma_f32_16x16x32_f16(a, bz, zacc[mt],0,0,0);
      racc[mt] = __builtin_amdgcn_mfma_f32_16x16x32_f16(a, br, racc[mt],0,0,0);
    }
  }
  __syncthreads();   // all reads of raw h done

  // --- elementwise: one b32 read gives {hl,hr}; write back {r*hl, r*hr}; carry z,s packed f16 ---
  uint zp[MT][2], sp[MT][2];
  const float bzv = bc[col], brv = bc[128+col];
  #pragma unroll
  for (int mt=0; mt<MT; mt++){
    union { half_t h[4]; uint u[2]; } pz, ps;
    #pragma unroll
    for (int q=0; q<4; q++){
      int row = mt*16 + lq + q;
      uint pr = *(uint*)&xs[row][2*col];
      union { uint u; half_t h[2]; } io; io.u = pr;
      float hl = (float)io.h[0];
      float hr = (float)io.h[1];
      float z  = sigm(zacc[mt][q] + bzv);
      float rv = sigm(racc[mt][q] + brv);
      pz.h[q] = (half_t)z;
      ps.h[q] = (half_t)(hl + hr);
      io.h[0] = (half_t)(rv*hl);
      io.h[1] = (half_t)(rv*hr);
      *(uint*)&xs[row][2*col] = io.u;
    }
    zp[mt][0]=pz.u[0]; zp[mt][1]=pz.u[1];
    sp[mt][0]=ps.u[0]; sp[mt][1]=ps.u[1];
  }
  __syncthreads();

  // --- h~ GEMM over interleaved (r*hl,r*hr) ---
  f32x4 ha[MT] = {};
  const half_t* uhp = Uh_f + ((w*8)*64 + l)*8;
  f16x8 bh_n = *(const f16x8*)uhp;
  #pragma unroll
  for (int ks=0; ks<8; ks++){
    f16x8 bh = bh_n;
    if (ks < 7) bh_n = *(const f16x8*)(uhp + (ks+1)*512);
    #pragma unroll
    for (int mt=0; mt<MT; mt++){
      f16x8 a = *(const f16x8*)&xs[mt*16 + lr][ks*32 + lk];
      ha[mt] = __builtin_amdgcn_mfma_f32_16x16x32_f16(a, bh, ha[mt],0,0,0);
    }
  }
  // --- combine + store ---
  const float bhv = bc[256+col];
  #pragma unroll
  for (int mt=0; mt<MT; mt++){
    union { half_t h[4]; uint u[2]; } pz, ps;
    pz.u[0]=zp[mt][0]; pz.u[1]=zp[mt][1];
    ps.u[0]=sp[mt][0]; ps.u[1]=sp[mt][1];
    #pragma unroll
    for (int q=0; q<4; q++){
      int row = mt*16 + lq + q;
      float ht = tanh_(ha[mt][q] + bhv);
      float z  = (float)pz.h[q];
      float o  = z*(float)ps.h[q] + (1.f-z)*ht;
      size_t off = (size_t)(m0+row)*128 + col;
      if (last) outf[off] = o;
      else      hout[off] = (half_t)o;
    }
  }
}

extern "C" void kernel_launch(void* const* d_in, const int* in_sizes, int n_in,
                              void* d_out, int out_size, void* d_ws, size_t ws_size,
                              hipStream_t stream) {
  const int*   tokens = (const int*)  d_in[0];
  const float* emb    = (const float*)d_in[1];
  const float* Wz  = (const float*)d_in[2];  const float* bWz  = (const float*)d_in[3];
  const float* Uzl = (const float*)d_in[4];  const float* bUzl = (const float*)d_in[5];
  const float* Uzr = (const float*)d_in[6];  const float* bUzr = (const float*)d_in[7];
  const float* Wr  = (const float*)d_in[8];  const float* bWr  = (const float*)d_in[9];
  const float* Url = (const float*)d_in[10]; const float* bUrl = (const float*)d_in[11];
  const float* Urr = (const float*)d_in[12]; const float* bUrr = (const float*)d_in[13];
  const float* Wh  = (const float*)d_in[14]; const float* bWh  = (const float*)d_in[15];
  const float* Uhl = (const float*)d_in[16]; const float* bUhl = (const float*)d_in[17];
  const float* Uhr = (const float*)d_in[18]; const float* bUhr = (const float*)d_in[19];

  float*  bc = (float*)d_ws;
  half_t* wb = (half_t*)((char*)d_ws + 4096);
  half_t* Wz_f = wb;
  half_t* Wh_f = wb + 16384;
  half_t* Uz_f = wb + 32768;
  half_t* Ur_f = wb + 65536;
  half_t* Uh_f = wb + 98304;
  half_t* hA = (half_t*)((char*)d_ws + (1<<20));     // 262144*128 f16 = 67 MB
  half_t* hB = hA + (size_t)NTOK*128;                // 131072*128 f16 = 33.5 MB

  bias_k<<<1, 384, 0, stream>>>(bWz,bUzl,bUzr,bWr,bUrl,bUrr,bWh,bUhl,bUhr, bc);
  wprep_k<<<512, 256, 0, stream>>>(Wz,Wh,Uzl,Uzr,Url,Urr,Uhl,Uhr, wb);

  level0_k<8><<<NTOK/128, 512, 0, stream>>>(tokens, emb, Wz_f, Wh_f, bc, hA);

  const half_t* src = hA;
  half_t* other = hB;
  for (int lvl = 1; lvl <= 6; lvl++){
    int M = NB << (6 - lvl);           // 131072 .. 4096 output rows
    int last = (lvl == 6);
    half_t* dst = other;
    if (M >= 32768){
      tree_k<8><<<M/128, 512, 0, stream>>>(src, dst, (float*)d_out,
                                           Uz_f, Ur_f, Uh_f, bc, last);
    } else if (M >= 16384){
      tree_k<4><<<M/64, 512, 0, stream>>>(src, dst, (float*)d_out,
                                          Uz_f, Ur_f, Uh_f, bc, last);
    } else {
      tree_k<2><<<M/32, 512, 0, stream>>>(src, dst, (float*)d_out,
                                          Uz_f, Ur_f, Uh_f, bc, last);
    }
    other = (half_t*)src;
    src = dst;
  }
}

// Round 8
// 149.845 us; speedup vs baseline: 12.5095x; 1.1265x over previous
//
#include <hip/hip_runtime.h>

// EncoderTreeRNN — R8: vocab-table for level 0 + token-gather fused into tree L1.
// h1 depends only on token id  ->  t1[v] = (1-z)*tanh(...) over the 100k vocab (coalesced),
// tree L1 stages A-tiles by gathering t1 rows via tokens (f16, no h1 round-trip).
// Tree (word=0): z=sigm(hl Uzl+hr Uzr+bz), r=sigm(hl Url+hr Urr+br),
//                h~=tanh((r*hl)Uhl+(r*hr)Uhr+bh), out=z*(hl+hr)+(1-z)*h~
// K-dim of tree GEMMs PERMUTED (k'=2j -> hl[j], 2j+1 -> hr[j]); U rows permuted to match.
// Weights fragment-contiguous: frag(w,ks) = 64 lanes x 16B contiguous -> coalesced B-loads.

typedef _Float16 half_t;
typedef __attribute__((ext_vector_type(8))) _Float16 f16x8;
typedef __attribute__((ext_vector_type(4))) float f32x4;

#define NTOK 262144
#define NB 4096
#define NV 100000

__device__ __forceinline__ float sigm(float x){
  float e = __expf(-x);
  return __builtin_amdgcn_rcpf(1.0f + e);
}
__device__ __forceinline__ float tanh_(float x){
  float xc = fminf(fmaxf(x,-15.f),15.f);
  float e = __expf(2.f*xc);
  return (e - 1.f) * __builtin_amdgcn_rcpf(e + 1.f);
}

// bc[0:128)=bWz+bUzl+bUzr, [128:256)=bWr+bUrl+bUrr, [256:384)=bWh+bUhl+bUhr
__global__ void bias_k(const float* bWz,const float* bUzl,const float* bUzr,
                       const float* bWr,const float* bUrl,const float* bUrr,
                       const float* bWh,const float* bUhl,const float* bUhr, float* bc){
  int j = threadIdx.x;
  if (j < 128)      bc[j] = bWz[j]+bUzl[j]+bUzr[j];
  else if (j < 256){ int i=j-128; bc[j] = bWr[i]+bUrl[i]+bUrr[i]; }
  else if (j < 384){ int i=j-256; bc[j] = bWh[i]+bUhl[i]+bUhr[i]; }
}

// Fragment-contiguous weights (as R7).
__global__ __launch_bounds__(256) void wprep_k(
    const float* Wz, const float* Wh,
    const float* Uzl,const float* Uzr,const float* Url,const float* Urr,
    const float* Uhl,const float* Uhr, half_t* wb){
  int idx = blockIdx.x*256 + threadIdx.x;           // 131072 total
  if (idx < 32768){                                  // Wz_f, Wh_f
    const float* W = (idx < 16384) ? Wz : Wh;
    int t = idx & 16383;
    int w = t >> 11, ks = (t >> 9) & 3, l = (t >> 3) & 63, j = t & 7;
    int n = w*16 + (l & 15);
    int k = ks*32 + ((l >> 4) << 3) + j;
    wb[idx] = (half_t)W[k*128 + n];
  } else {                                           // Uz_f, Ur_f, Uh_f (K interleaved)
    int t = idx - 32768;
    int mat = t >> 15;                               // 0=z,1=r,2=h
    t &= 32767;
    int w = t >> 12, ks = (t >> 9) & 7, l = (t >> 3) & 63, j = t & 7;
    int n = w*16 + (l & 15);
    int kp = ks*32 + ((l >> 4) << 3) + j;            // 0..255 interleaved
    int k = kp >> 1;
    const float* U;
    if (mat == 0) U = (kp & 1) ? Uzr : Uzl;
    else if (mat == 1) U = (kp & 1) ? Urr : Url;
    else U = (kp & 1) ? Uhr : Uhl;
    wb[idx] = (half_t)U[k*128 + n];
  }
}

// Vocab table: t1[v] = (1-z)*tanh(xWh+bh), z=sigm(xWz+bz), x=emb[v]. Sequential, coalesced.
// MT*16 rows x 128 cols per block, 8 waves x 16 cols. K=128. Guard rows >= NV.
template<int MT>
__global__ __launch_bounds__(512, 4) void h1tab_k(
    const float* __restrict__ emb,
    const half_t* __restrict__ Wz_f, const half_t* __restrict__ Wh_f,
    const float* __restrict__ bc, half_t* __restrict__ t1)
{
  __shared__ __align__(16) _Float16 xs[MT*16][136];   // 272B stride === 4 dw mod 32
  const int tid = threadIdx.x;
  const int m0  = blockIdx.x*(MT*16);
  #pragma unroll
  for (int it = 0; it < MT; it++){
    int idx = it*512 + tid;
    int m = idx >> 5, c = idx & 31;
    int row = m0 + m; if (row >= NV) row = 0;        // clamp (stores guarded)
    float4 v = ((const float4*)(emb + (size_t)row*128))[c];
    union { half_t h[4]; ushort4 u; } p;
    p.h[0]=(half_t)v.x; p.h[1]=(half_t)v.y; p.h[2]=(half_t)v.z; p.h[3]=(half_t)v.w;
    *(ushort4*)&xs[m][c*4] = p.u;
  }
  __syncthreads();
  const int w = tid>>6, l = tid&63;
  const int lr = l&15, lk = (l>>4)*8, lq = (l>>4)*4;
  const int col = w*16 + lr;

  f32x4 zacc[MT] = {}; f32x4 hacc[MT] = {};
  const half_t* wzp = Wz_f + ((w*4)*64 + l)*8;
  const half_t* whp = Wh_f + ((w*4)*64 + l)*8;
  f16x8 bz_n = *(const f16x8*)wzp;
  f16x8 bh_n = *(const f16x8*)whp;
  #pragma unroll
  for (int ks=0; ks<4; ks++){
    f16x8 bz = bz_n, bh = bh_n;
    if (ks < 3){
      bz_n = *(const f16x8*)(wzp + (ks+1)*512);
      bh_n = *(const f16x8*)(whp + (ks+1)*512);
    }
    #pragma unroll
    for (int mt=0; mt<MT; mt++){
      f16x8 a = *(const f16x8*)&xs[mt*16 + lr][ks*32 + lk];
      zacc[mt] = __builtin_amdgcn_mfma_f32_16x16x32_f16(a, bz, zacc[mt],0,0,0);
      hacc[mt] = __builtin_amdgcn_mfma_f32_16x16x32_f16(a, bh, hacc[mt],0,0,0);
    }
  }
  const float bzv = bc[col], bhv = bc[256+col];
  #pragma unroll
  for (int mt=0; mt<MT; mt++){
    #pragma unroll
    for (int q=0; q<4; q++){
      int row = m0 + mt*16 + lq + q;
      if (row < NV){
        float z  = sigm(zacc[mt][q] + bzv);
        float ht = tanh_(hacc[mt][q] + bhv);
        t1[(size_t)row*128 + col] = (half_t)((1.f-z)*ht);
      }
    }
  }
}

// Tree level. GATHER=1: stage A-tile from t1 via tokens; else contiguous from hin.
// MT*16 out-rows x 128 cols per block, 8 waves x 16 cols. K=256 interleaved.
template<int MT, int GATHER>
__global__ __launch_bounds__(512, 4) void tree_k(
    const half_t* __restrict__ hin, const int* __restrict__ tokens,
    half_t* __restrict__ hout, float* __restrict__ outf,
    const half_t* __restrict__ Uz_f, const half_t* __restrict__ Ur_f, const half_t* __restrict__ Uh_f,
    const float* __restrict__ bc, int last)
{
  __shared__ __align__(16) _Float16 xs[MT*16][264];   // 528B stride === 4 dw mod 32
  const int tid = threadIdx.x;
  const int m0  = blockIdx.x*(MT*16);
  // stage interleaved: xs[m][2j] = hl[m][j], xs[m][2j+1] = hr[m][j]
  #pragma unroll
  for (int it = 0; it < MT; it++){
    int idx = it*512 + tid;                 // MT*16 rows x 32 chunks (4 j-pairs each)
    int m = idx >> 5, c = idx & 31;
    const half_t *pl, *pr;
    if (GATHER){
      int tl = tokens[2*(m0+m)], tr = tokens[2*(m0+m)+1];
      pl = hin + (size_t)tl*128 + c*4;
      pr = hin + (size_t)tr*128 + c*4;
    } else {
      size_t base = (size_t)(2*(m0+m))*128 + c*4;
      pl = hin + base;
      pr = hin + base + 128;
    }
    uint2 A  = *(const uint2*)pl;
    uint2 Bv = *(const uint2*)pr;
    uint4 o;
    o.x = (A.x & 0xFFFFu) | (Bv.x << 16);
    o.y = (A.x >> 16)     | (Bv.x & 0xFFFF0000u);
    o.z = (A.y & 0xFFFFu) | (Bv.y << 16);
    o.w = (A.y >> 16)     | (Bv.y & 0xFFFF0000u);
    *(uint4*)&xs[m][c*8] = o;
  }
  __syncthreads();
  const int w = tid>>6, l = tid&63;
  const int lr = l&15, lk = (l>>4)*8, lq = (l>>4)*4;
  const int col = w*16 + lr;

  // --- z & r GEMMs (shared A-frags, coalesced frag-layout B) ---
  f32x4 zacc[MT] = {}; f32x4 racc[MT] = {};
  const half_t* uzp = Uz_f + ((w*8)*64 + l)*8;
  const half_t* urp = Ur_f + ((w*8)*64 + l)*8;
  f16x8 bz_n = *(const f16x8*)uzp;
  f16x8 br_n = *(const f16x8*)urp;
  #pragma unroll
  for (int ks=0; ks<8; ks++){
    f16x8 bz = bz_n, br = br_n;
    if (ks < 7){
      bz_n = *(const f16x8*)(uzp + (ks+1)*512);
      br_n = *(const f16x8*)(urp + (ks+1)*512);
    }
    #pragma unroll
    for (int mt=0; mt<MT; mt++){
      f16x8 a = *(const f16x8*)&xs[mt*16 + lr][ks*32 + lk];
      zacc[mt] = __builtin_amdgcn_mfma_f32_16x16x32_f16(a, bz, zacc[mt],0,0,0);
      racc[mt] = __builtin_amdgcn_mfma_f32_16x16x32_f16(a, br, racc[mt],0,0,0);
    }
  }
  __syncthreads();   // all reads of raw h done

  // --- elementwise: one b32 read -> {hl,hr}; write back {r*hl,r*hr}; carry z,s packed f16 ---
  uint zp[MT][2], sp[MT][2];
  const float bzv = bc[col], brv = bc[128+col];
  #pragma unroll
  for (int mt=0; mt<MT; mt++){
    union { half_t h[4]; uint u[2]; } pz, ps;
    #pragma unroll
    for (int q=0; q<4; q++){
      int row = mt*16 + lq + q;
      union { uint u; half_t h[2]; } io;
      io.u = *(uint*)&xs[row][2*col];
      float hl = (float)io.h[0];
      float hr = (float)io.h[1];
      float z  = sigm(zacc[mt][q] + bzv);
      float rv = sigm(racc[mt][q] + brv);
      pz.h[q] = (half_t)z;
      ps.h[q] = (half_t)(hl + hr);
      io.h[0] = (half_t)(rv*hl);
      io.h[1] = (half_t)(rv*hr);
      *(uint*)&xs[row][2*col] = io.u;
    }
    zp[mt][0]=pz.u[0]; zp[mt][1]=pz.u[1];
    sp[mt][0]=ps.u[0]; sp[mt][1]=ps.u[1];
  }
  __syncthreads();

  // --- h~ GEMM over interleaved (r*hl,r*hr) ---
  f32x4 ha[MT] = {};
  const half_t* uhp = Uh_f + ((w*8)*64 + l)*8;
  f16x8 bh_n = *(const f16x8*)uhp;
  #pragma unroll
  for (int ks=0; ks<8; ks++){
    f16x8 bh = bh_n;
    if (ks < 7) bh_n = *(const f16x8*)(uhp + (ks+1)*512);
    #pragma unroll
    for (int mt=0; mt<MT; mt++){
      f16x8 a = *(const f16x8*)&xs[mt*16 + lr][ks*32 + lk];
      ha[mt] = __builtin_amdgcn_mfma_f32_16x16x32_f16(a, bh, ha[mt],0,0,0);
    }
  }
  // --- combine + store ---
  const float bhv = bc[256+col];
  #pragma unroll
  for (int mt=0; mt<MT; mt++){
    union { half_t h[4]; uint u[2]; } pz, ps;
    pz.u[0]=zp[mt][0]; pz.u[1]=zp[mt][1];
    ps.u[0]=sp[mt][0]; ps.u[1]=sp[mt][1];
    #pragma unroll
    for (int q=0; q<4; q++){
      int row = mt*16 + lq + q;
      float ht = tanh_(ha[mt][q] + bhv);
      float z  = (float)pz.h[q];
      float o  = z*(float)ps.h[q] + (1.f-z)*ht;
      size_t off = (size_t)(m0+row)*128 + col;
      if (last) outf[off] = o;
      else      hout[off] = (half_t)o;
    }
  }
}

extern "C" void kernel_launch(void* const* d_in, const int* in_sizes, int n_in,
                              void* d_out, int out_size, void* d_ws, size_t ws_size,
                              hipStream_t stream) {
  const int*   tokens = (const int*)  d_in[0];
  const float* emb    = (const float*)d_in[1];
  const float* Wz  = (const float*)d_in[2];  const float* bWz  = (const float*)d_in[3];
  const float* Uzl = (const float*)d_in[4];  const float* bUzl = (const float*)d_in[5];
  const float* Uzr = (const float*)d_in[6];  const float* bUzr = (const float*)d_in[7];
  const float* Wr  = (const float*)d_in[8];  const float* bWr  = (const float*)d_in[9];
  const float* Url = (const float*)d_in[10]; const float* bUrl = (const float*)d_in[11];
  const float* Urr = (const float*)d_in[12]; const float* bUrr = (const float*)d_in[13];
  const float* Wh  = (const float*)d_in[14]; const float* bWh  = (const float*)d_in[15];
  const float* Uhl = (const float*)d_in[16]; const float* bUhl = (const float*)d_in[17];
  const float* Uhr = (const float*)d_in[18]; const float* bUhr = (const float*)d_in[19];

  float*  bc = (float*)d_ws;
  half_t* wb = (half_t*)((char*)d_ws + 4096);
  half_t* Wz_f = wb;
  half_t* Wh_f = wb + 16384;
  half_t* Uz_f = wb + 32768;
  half_t* Ur_f = wb + 65536;
  half_t* Uh_f = wb + 98304;
  half_t* t1 = (half_t*)((char*)d_ws + (1<<20));     // 100000*128 f16 = 25.6 MB
  half_t* hA = t1 + (size_t)NV*128;                  // 131072*128 f16 = 33.5 MB
  half_t* hB = hA + (size_t)(NTOK/2)*128;            // 65536*128 f16 = 16.8 MB

  bias_k<<<1, 384, 0, stream>>>(bWz,bUzl,bUzr,bWr,bUrl,bUrr,bWh,bUhl,bUhr, bc);
  wprep_k<<<512, 256, 0, stream>>>(Wz,Wh,Uzl,Uzr,Url,Urr,Uhl,Uhr, wb);

  h1tab_k<8><<<(NV + 127)/128, 512, 0, stream>>>(emb, Wz_f, Wh_f, bc, t1);

  // L1: gather from t1 via tokens. M = 131072.
  tree_k<8,1><<<(NTOK/2)/128, 512, 0, stream>>>(t1, tokens, hA, (float*)d_out,
                                                Uz_f, Ur_f, Uh_f, bc, 0);
  // L2..L6
  const half_t* src = hA;
  half_t* other = hB;
  for (int lvl = 2; lvl <= 6; lvl++){
    int M = NB << (6 - lvl);           // 65536 .. 4096 output rows
    int last = (lvl == 6);
    half_t* dst = other;
    if (M >= 32768){
      tree_k<8,0><<<M/128, 512, 0, stream>>>(src, tokens, dst, (float*)d_out,
                                             Uz_f, Ur_f, Uh_f, bc, last);
    } else if (M >= 16384){
      tree_k<4,0><<<M/64, 512, 0, stream>>>(src, tokens, dst, (float*)d_out,
                                            Uz_f, Ur_f, Uh_f, bc, last);
    } else {
      tree_k<2,0><<<M/32, 512, 0, stream>>>(src, tokens, dst, (float*)d_out,
                                            Uz_f, Ur_f, Uh_f, bc, last);
    }
    other = (half_t*)src;
    src = dst;
  }
}